// Round 1
// baseline (2194.117 us; speedup 1.0000x reference)
//
#include <hip/hip_runtime.h>
#include <hip/hip_bf16.h>

// out[o,i,m,n] = sum_{d,j} Wd[i,j] * X(o, m+d-2, j, (n-1)%56)   (m>=1, zero-padded taps)
// X(o,mm,j,n) = x[o, l, n, k] with 56k+l = 64*mm + j
// m==0 handled by fixup kernel (wrap rows 54/55 with unmerged weights).

typedef __bf16 bf16x8 __attribute__((ext_vector_type(8)));
typedef float f32x4 __attribute__((ext_vector_type(4)));

#define YSTRIDE 456   // 448 cols + 8 pad (bf16), row stride 912 B (16B-multiple)
#define FSTRIDE 264   // fixup: 256 + 8

__device__ __forceinline__ unsigned short f2bf(float f) {
    unsigned int u = __float_as_uint(f);
    unsigned int r = (u + 0x7fffu + ((u >> 16) & 1u)) >> 16;
    return (unsigned short)r;
}

// Pre-swizzle weights into MFMA A-operand fragment order.
// Element (fragFlat=kkc*4+ic, lane, t):  i = ic*16 + (lane&15), kk = kkc*32 + (lane>>4)*8 + t
// ushort index = fragFlat*512 + lane*8 + t = tid.  Main set at [0,16384), fixup at [16384,32768).
__global__ void prep_w(const float* __restrict__ w, unsigned short* __restrict__ ws) {
    int tid = blockIdx.x * blockDim.x + threadIdx.x;   // [0,16384)
    int t    = tid & 7;
    int lane = (tid >> 3) & 63;
    int f    = tid >> 9;                               // [0,32)
    int kkc = f >> 2, ic = f & 3;
    int i  = ic * 16 + (lane & 15);
    int kk = kkc * 32 + ((lane >> 4) << 3) + t;
    int d = kk >> 6, j = kk & 63;
    // w[i][r][lp][j], strides (384,128,64,1)
    #define WREF(r, lp) w[((i * 3 + (r)) * 2 + (lp)) * 64 + j]
    float vm, vf;
    if (d == 0)      { vm = WREF(0,1);              vf = WREF(0,1); }
    else if (d == 1) { vm = WREF(1,1) + WREF(0,0);  vf = WREF(1,1); }
    else if (d == 2) { vm = WREF(2,1) + WREF(1,0);  vf = WREF(1,0); }
    else             { vm = WREF(2,0);              vf = WREF(2,0); }
    #undef WREF
    ws[tid]         = f2bf(vm);
    ws[16384 + tid] = f2bf(vf);
}

// Shared GEMM core: A = weight frags (regs), B = y_lds rows (rho = n'), D rows = i, cols = rho.
__device__ __forceinline__ void gemm_and_store(
    const unsigned short* __restrict__ y, int ystride, int colbase,
    const unsigned short* __restrict__ wfr,   // frag base (ushort*)
    float* __restrict__ outom)                // out + ((o*64+0)*56 + m)*56
{
    int tid = threadIdx.x;
    int wid = tid >> 6, lane = tid & 63;
    int ih = wid >> 1, rh = wid & 1;
    int l15 = lane & 15, q = lane >> 4;

    bf16x8 wf[2][8];
    #pragma unroll
    for (int a = 0; a < 2; ++a) {
        int ic = ih * 2 + a;
        #pragma unroll
        for (int kkc = 0; kkc < 8; ++kkc)
            wf[a][kkc] = *(const bf16x8*)(wfr + (kkc * 4 + ic) * 512 + lane * 8);
    }

    f32x4 acc[2][2];
    #pragma unroll
    for (int a = 0; a < 2; ++a)
        #pragma unroll
        for (int b = 0; b < 2; ++b)
            acc[a][b] = (f32x4){0.f, 0.f, 0.f, 0.f};

    #pragma unroll
    for (int kkc = 0; kkc < 8; ++kkc) {
        bf16x8 yf[2];
        #pragma unroll
        for (int b = 0; b < 2; ++b) {
            int rho = rh * 32 + b * 16 + l15;
            yf[b] = *(const bf16x8*)&y[rho * ystride + colbase + kkc * 32 + (q << 3)];
        }
        #pragma unroll
        for (int a = 0; a < 2; ++a)
            #pragma unroll
            for (int b = 0; b < 2; ++b)
                acc[a][b] = __builtin_amdgcn_mfma_f32_16x16x32_bf16(wf[a][kkc], yf[b], acc[a][b], 0, 0, 0);
    }

    #pragma unroll
    for (int a = 0; a < 2; ++a) {
        int ibase = (ih * 2 + a) * 16 + q * 4;
        #pragma unroll
        for (int b = 0; b < 2; ++b) {
            int rho = rh * 32 + b * 16 + l15;
            if (rho < 56) {
                int n = rho + 1; if (n >= 56) n = 0;
                #pragma unroll
                for (int r = 0; r < 4; ++r)
                    outom[(size_t)(ibase + r) * 3136 + n] = acc[a][b][r];
            }
        }
    }
}

__global__ __launch_bounds__(256, 2)
void conv_main(const float* __restrict__ x, const unsigned short* __restrict__ wfr,
               float* __restrict__ out) {
    __shared__ __align__(16) unsigned short y[64 * YSTRIDE];
    int b  = blockIdx.x;
    int o  = b / 14;
    int m0 = (b - o * 14) * 4;
    int e0 = (m0 - 2) * 64;
    int tid = threadIdx.x;

    if (m0 == 0 || m0 == 52) {                 // slab has cols outside image -> zero
        uint4 z = {0u, 0u, 0u, 0u};
        for (int idx = tid; idx < 64 * YSTRIDE / 8; idx += 256)
            ((uint4*)y)[idx] = z;
        __syncthreads();
    }

    // Stage: y[n][e-e0] = bf16(x[o, e%56, n, e/56]) for e in [e0, e0+448) ∩ [0,3584)
    const float* xo = x + (size_t)o * 200704;
    for (int it = 0; it < 37; ++it) {
        int idx = it * 256 + tid;
        if (idx < 9408) {
            int p = idx / 3, seg = idx - p * 3;
            int l = p / 56, n = p - l * 56;
            int tnum = e0 - l + 55;
            int klo = tnum > 0 ? tnum / 56 : 0;         // ceil((e0-l)/56) clamped to 0
            int k4 = (klo >> 2) + seg;
            if (k4 <= 15) {
                float4 v = *(const float4*)(xo + ((l * 56 + n) * 64 + (k4 << 2)));
                int col = 56 * (k4 << 2) + l - e0;       // component c adds 56*c
                if ((unsigned)col         < 448u) y[n * YSTRIDE + col]       = f2bf(v.x);
                if ((unsigned)(col + 56)  < 448u) y[n * YSTRIDE + col + 56]  = f2bf(v.y);
                if ((unsigned)(col + 112) < 448u) y[n * YSTRIDE + col + 112] = f2bf(v.z);
                if ((unsigned)(col + 168) < 448u) y[n * YSTRIDE + col + 168] = f2bf(v.w);
            }
        }
    }
    __syncthreads();

    float* outo = out + (size_t)o * 200704;
    for (int mt = 0; mt < 4; ++mt)
        gemm_and_store(y, YSTRIDE, mt * 64, wfr, outo + (size_t)(m0 + mt) * 56);
}

// m==0 rows: out[o,i,0,n] = sum_j w[i,0,1,j]X(54) + w[i,1,1,j]X(55) + w[i,1,0,j]X(0) + w[i,2,0,j]X(1)
__global__ __launch_bounds__(256, 2)
void conv_fix(const float* __restrict__ x, const unsigned short* __restrict__ wfr,
              float* __restrict__ out) {
    __shared__ __align__(16) unsigned short y[64 * FSTRIDE];
    int o = blockIdx.x;
    int tid = threadIdx.x;
    const float* xo = x + (size_t)o * 200704;
    // dd in [0,128) <- e in [3456,3584);  dd in [128,256) <- e in [0,128)
    for (int it = 0; it < 25; ++it) {
        int idx = it * 256 + tid;
        if (idx < 6272) {
            int p = idx >> 1, g = idx & 1;
            int l = p / 56, n = p - l * 56;
            int k4 = g ? 15 : 0;
            float4 v = *(const float4*)(xo + ((l * 56 + n) * 64 + (k4 << 2)));
            float vv[4] = {v.x, v.y, v.z, v.w};
            #pragma unroll
            for (int c = 0; c < 4; ++c) {
                int e = 56 * ((k4 << 2) + c) + l;
                int dd = (e < 128) ? (128 + e) : ((e >= 3456) ? (e - 3456) : -1);
                if (dd >= 0) y[n * FSTRIDE + dd] = f2bf(vv[c]);
            }
        }
    }
    __syncthreads();
    gemm_and_store(y, FSTRIDE, 0, wfr + 16384, out + (size_t)o * 200704);
}

extern "C" void kernel_launch(void* const* d_in, const int* in_sizes, int n_in,
                              void* d_out, int out_size, void* d_ws, size_t ws_size,
                              hipStream_t stream) {
    const float* x = (const float*)d_in[0];
    const float* w = (const float*)d_in[1];
    float* out = (float*)d_out;
    unsigned short* wsp = (unsigned short*)d_ws;   // needs 64 KiB
    prep_w<<<64, 256, 0, stream>>>(w, wsp);
    conv_main<<<14336, 256, 0, stream>>>(x, wsp, out);
    conv_fix<<<1024, 256, 0, stream>>>(x, wsp, out);
}